// Round 24
// baseline (331.791 us; speedup 1.0000x reference)
//
#include <hip/hip_runtime.h>
#include <hip/hip_bf16.h>

#define W 64
#define D 256
#define NH 8

typedef unsigned short u16;
typedef unsigned int u32;
typedef __attribute__((ext_vector_type(8))) short bf16x8;
typedef __attribute__((ext_vector_type(4))) float f32x4;

// Native RNE f32->bf16 cast: compiler emits v_cvt_pk_bf16_f32 for pairs.
__device__ __forceinline__ u16 bfc(float f) {
    __hip_bfloat16 h = __float2bfloat16(f);
    return *reinterpret_cast<u16*>(&h);
}

// Sum over the 16-lane DPP row (VALU pipe, not DS): ror8, ror4, quad_perms.
__device__ __forceinline__ float row16_sum(float x) {
    int t;
    t = __builtin_amdgcn_update_dpp(0, __builtin_bit_cast(int, x), 0x128, 0xf, 0xf, true); // row_ror:8
    x += __builtin_bit_cast(float, t);
    t = __builtin_amdgcn_update_dpp(0, __builtin_bit_cast(int, x), 0x124, 0xf, 0xf, true); // row_ror:4
    x += __builtin_bit_cast(float, t);
    t = __builtin_amdgcn_update_dpp(0, __builtin_bit_cast(int, x), 78, 0xf, 0xf, true);    // quad_perm [2,3,0,1]
    x += __builtin_bit_cast(float, t);
    t = __builtin_amdgcn_update_dpp(0, __builtin_bit_cast(int, x), 177, 0xf, 0xf, true);   // quad_perm [1,0,3,2]
    x += __builtin_bit_cast(float, t);
    return x;
}

// ---------------- LDS layout (bytes) ----------------
// xs   : [64][264] u16   x bf16 staging; dead after QKV; aliased by attn_out 33792
// buf  : per-wave [16][72] u16 transposer (q/k 2-pass, v 2-pass, P)           2304 x 8
// bias : [8][128] f32 rel-pos bias table                                      4096
// total 56320 -> 2 blocks/CU (register-capped: 64 VGPR + ~32 AGPR = 96/wave).
// R19/R23 basin-floor kernel + swapped-operand proj epilogue:
//  phase 3 computes C = mfma(A=wproj-frag, B=ao-frag) so lane=token,
//  regs=4 consecutive channels -> 8 dwordx4 stores/thread (was 32 scalar).
//  Contraction exact: both operands index k by the same ks*32+g*8 pattern
//  (R12-verified consistent-permutation argument); C-layout col=lane,
//  row=reg per m89/m91. Reads and all earlier phases byte-identical.
// Full lgkmcnt(0) drains kept verbatim: the no-spill regalloc anchor
// (R9/R13/R14/R16/R22: any removal/replacement/perturbation spills).
#define XS_ROW 264
#define BUF_ROW 72
#define OFF_BUF 33792
#define OFF_BIAS 52224

__global__ __launch_bounds__(512, 4) void win_attn_final2(
    const float* __restrict__ x, const float* __restrict__ bqkv,
    const float* __restrict__ bproj, const float* __restrict__ relb,
    const u16* __restrict__ wqkvT, const u16* __restrict__ wprojT,
    float* __restrict__ out)
{
    __shared__ __align__(16) char smem[56320];

    const int tid  = threadIdx.x;
    const int lane = tid & 63;
    const int h    = tid >> 6;      // wave index == head
    const int l15  = lane & 15;
    const int g    = lane >> 4;
    const int w    = blockIdx.x;

    u16*   xs      = (u16*)smem;
    u16*   buf     = (u16*)(smem + OFF_BUF) + h * 16 * BUF_ROW;
    float* bias_ld = (float*)(smem + OFF_BIAS);

    const f32x4 z4 = {0.f, 0.f, 0.f, 0.f};
    const float scale = 0.17677669529663687f;   // 1/sqrt(32)

    // ---------- Phase 0: bias table + stage x window -> LDS bf16 ----------
    for (int i = tid; i < NH * 127; i += 512)
        bias_ld[(i / 127) * 128 + (i % 127)] = relb[i];

    const float* xw = x + (size_t)w * (W * D);
    #pragma unroll
    for (int i = 0; i < 8; ++i) {
        int e = i * 2048 + tid * 4;
        int row = e >> 8, col = e & 255;
        float4 v = *(const float4*)(xw + e);
        ushort4 b;
        b.x = bfc(v.x); b.y = bfc(v.y); b.z = bfc(v.z); b.w = bfc(v.w);
        *(ushort4*)(xs + row * XS_ROW + col) = b;
    }
    __syncthreads();

    // ---------- Phase 1: QKV for head h; fragments kept in registers ----------
    bf16x8 qf[4], kf[4], vf[2][2];

    #pragma unroll
    for (int mat = 0; mat < 3; ++mat) {
        f32x4 acc[2][4];
        #pragma unroll
        for (int ct = 0; ct < 2; ++ct)
            #pragma unroll
            for (int rt = 0; rt < 4; ++rt)
                acc[ct][rt] = z4;

        const u16* bp0 = wqkvT + (size_t)(mat * 256 + h * 32 + l15) * 256;
        const u16* bp1 = bp0 + 16 * 256;
        #pragma unroll
        for (int ks = 0; ks < 8; ++ks) {
            bf16x8 b0 = *(const bf16x8*)(bp0 + ks * 32 + g * 8);
            bf16x8 b1 = *(const bf16x8*)(bp1 + ks * 32 + g * 8);
            #pragma unroll
            for (int rt = 0; rt < 4; ++rt) {
                bf16x8 a = *(const bf16x8*)(xs + (16 * rt + l15) * XS_ROW + ks * 32 + g * 8);
                acc[0][rt] = __builtin_amdgcn_mfma_f32_16x16x32_bf16(a, b0, acc[0][rt], 0, 0, 0);
                acc[1][rt] = __builtin_amdgcn_mfma_f32_16x16x32_bf16(a, b1, acc[1][rt], 0, 0, 0);
            }
        }
        const float bias0 = bqkv[mat * 256 + h * 32 + l15];
        const float bias1 = bqkv[mat * 256 + h * 32 + 16 + l15];

        asm volatile("s_waitcnt lgkmcnt(0)" ::: "memory");   // WAR: prior buf reads done
        if (mat < 2) {
            // sigma32: channel 16*ct + l15 -> column 2*l15 + ct. Packed u32 writes.
            // q gets scale folded in; k unscaled. 2 row-tiles per pass.
            const float mul = (mat == 0) ? scale : 1.0f;
            #pragma unroll
            for (int rp = 0; rp < 2; ++rp) {
                #pragma unroll
                for (int rtl = 0; rtl < 2; ++rtl)
                    #pragma unroll
                    for (int r = 0; r < 4; ++r) {
                        u32 lo = bfc((acc[0][2 * rp + rtl][r] + bias0) * mul);
                        u32 hi = bfc((acc[1][2 * rp + rtl][r] + bias1) * mul);
                        *(u32*)(buf + (4 * g + r) * BUF_ROW + rtl * 32 + 2 * l15) =
                            lo | (hi << 16);
                    }
                asm volatile("s_waitcnt lgkmcnt(0)" ::: "memory");
                #pragma unroll
                for (int rtl = 0; rtl < 2; ++rtl) {
                    bf16x8 fr = *(const bf16x8*)(buf + l15 * BUF_ROW + rtl * 32 + g * 8);
                    if (mat == 0) qf[2 * rp + rtl] = fr; else kf[2 * rp + rtl] = fr;
                }
                asm volatile("s_waitcnt lgkmcnt(0)" ::: "memory");   // WAR before next pass
            }
        } else {
            // sigma64 on tokens: token t -> column 4*(t&15) + (t>>4).
            // t = 16*rt + 4*g + r2 -> column 16*g + 4*r2 + rt: pack across rt.
            #pragma unroll
            for (int cd = 0; cd < 2; ++cd) {
                const float bias = cd ? bias1 : bias0;
                #pragma unroll
                for (int r2 = 0; r2 < 4; ++r2) {
                    ushort4 pk;
                    pk.x = bfc(acc[cd][0][r2] + bias);
                    pk.y = bfc(acc[cd][1][r2] + bias);
                    pk.z = bfc(acc[cd][2][r2] + bias);
                    pk.w = bfc(acc[cd][3][r2] + bias);
                    *(ushort4*)(buf + l15 * BUF_ROW + 16 * g + 4 * r2) = pk;
                }
                asm volatile("s_waitcnt lgkmcnt(0)" ::: "memory");
                #pragma unroll
                for (int ks = 0; ks < 2; ++ks)
                    vf[ks][cd] = *(const bf16x8*)(buf + l15 * BUF_ROW + ks * 32 + g * 8);
                asm volatile("s_waitcnt lgkmcnt(0)" ::: "memory");   // WAR before next pass
            }
        }
    }
    __syncthreads();   // all xs reads done -> ao may alias xs

    // ---------- Phase 2: attention (wave-private; P via buf; bias via LDS) ----------
    const float* b2 = bias_ld + h * 128;
    u16* ao = xs;

    #pragma unroll
    for (int rt = 0; rt < 4; ++rt) {
        f32x4 s[4];
        #pragma unroll
        for (int ct = 0; ct < 4; ++ct)
            s[ct] = __builtin_amdgcn_mfma_f32_16x16x32_bf16(qf[rt], kf[ct], z4, 0, 0, 0);

        asm volatile("s_waitcnt lgkmcnt(0)" ::: "memory");   // WAR: prev rt's pf reads done
        float psum[4];
        #pragma unroll
        for (int r = 0; r < 4; ++r) {
            const int qtok = 16 * rt + 4 * g + r;
            // P[q][k]: token k = 16*ct + l15 stored at column 4*l15 + ct (sigma64)
            float e0 = __expf(s[0][r] + b2[     l15 - qtok + 63]);
            float e1 = __expf(s[1][r] + b2[16 + l15 - qtok + 63]);
            float e2 = __expf(s[2][r] + b2[32 + l15 - qtok + 63]);
            float e3 = __expf(s[3][r] + b2[48 + l15 - qtok + 63]);
            psum[r] = (e0 + e1) + (e2 + e3);
            ushort4 pk;
            pk.x = bfc(e0); pk.y = bfc(e1); pk.z = bfc(e2); pk.w = bfc(e3);
            *(ushort4*)(buf + (4 * g + r) * BUF_ROW + 4 * l15) = pk;
        }
        float inv[4];
        #pragma unroll
        for (int r = 0; r < 4; ++r)
            inv[r] = 1.0f / row16_sum(psum[r]);

        asm volatile("s_waitcnt lgkmcnt(0)" ::: "memory");
        bf16x8 pf0 = *(const bf16x8*)(buf + l15 * BUF_ROW + g * 8);
        bf16x8 pf1 = *(const bf16x8*)(buf + l15 * BUF_ROW + 32 + g * 8);
        #pragma unroll
        for (int cd = 0; cd < 2; ++cd) {
            f32x4 o = __builtin_amdgcn_mfma_f32_16x16x32_bf16(pf0, vf[0][cd], z4, 0, 0, 0);
            o = __builtin_amdgcn_mfma_f32_16x16x32_bf16(pf1, vf[1][cd], o, 0, 0, 0);
            #pragma unroll
            for (int r = 0; r < 4; ++r)
                ao[(16 * rt + 4 * g + r) * XS_ROW + h * 32 + cd * 16 + l15] = bfc(o[r] * inv[r]);
        }
        asm volatile("s_waitcnt lgkmcnt(0)" ::: "memory");   // WAR before next rt
    }
    __syncthreads();   // ao complete (cross-wave input to proj)

    // ---------- Phase 3: output projection, SWAPPED operands ----------
    // C = mfma(A = wproj-frag [row n], B = ao-frag [col tok]):
    // C[n][tok] with lane = tok, regs r = n = h*32 + mt*16 + 4*g + r
    // -> each lane stores 4 consecutive channels as one dwordx4.
    f32x4 pacc[2][4];   // [mt][nt]
    #pragma unroll
    for (int mt = 0; mt < 2; ++mt)
        #pragma unroll
        for (int nt = 0; nt < 4; ++nt)
            pacc[mt][nt] = z4;

    const u16* pp0 = wprojT + (size_t)(h * 32 + l15) * 256;
    const u16* pp1 = pp0 + 16 * 256;
    #pragma unroll
    for (int ks = 0; ks < 8; ++ks) {
        bf16x8 b0 = *(const bf16x8*)(pp0 + ks * 32 + g * 8);
        bf16x8 b1 = *(const bf16x8*)(pp1 + ks * 32 + g * 8);
        #pragma unroll
        for (int nt = 0; nt < 4; ++nt) {
            bf16x8 a = *(const bf16x8*)(ao + (16 * nt + l15) * XS_ROW + ks * 32 + g * 8);
            pacc[0][nt] = __builtin_amdgcn_mfma_f32_16x16x32_bf16(b0, a, pacc[0][nt], 0, 0, 0);
            pacc[1][nt] = __builtin_amdgcn_mfma_f32_16x16x32_bf16(b1, a, pacc[1][nt], 0, 0, 0);
        }
    }
    float* outw = out + (size_t)w * (W * D);
    #pragma unroll
    for (int mt = 0; mt < 2; ++mt) {
        const float* bpp = bproj + h * 32 + mt * 16 + 4 * g;
        f32x4 bv = {bpp[0], bpp[1], bpp[2], bpp[3]};
        #pragma unroll
        for (int nt = 0; nt < 4; ++nt) {
            f32x4 v = pacc[mt][nt] + bv;
            *(f32x4*)(outw + (16 * nt + l15) * D + h * 32 + mt * 16 + 4 * g) = v;
        }
    }
}

// Transpose + bf16-convert the weight matrices into workspace (L2-resident).
__global__ void prep_weights(const float* __restrict__ wqkv, const float* __restrict__ wproj,
                             u16* __restrict__ wqkvT, u16* __restrict__ wprojT)
{
    int i = blockIdx.x * 256 + threadIdx.x;
    if (i < 768 * 256) {
        int n = i >> 8, kk = i & 255;
        wqkvT[i] = bfc(wqkv[kk * 768 + n]);
    } else {
        int j = i - 768 * 256;
        int n = j >> 8, kk = j & 255;
        wprojT[j] = bfc(wproj[kk * 256 + n]);
    }
}

extern "C" void kernel_launch(void* const* d_in, const int* in_sizes, int n_in,
                              void* d_out, int out_size, void* d_ws, size_t ws_size,
                              hipStream_t stream)
{
    const float* x     = (const float*)d_in[0];
    const float* wqkv  = (const float*)d_in[1];
    const float* bqkv  = (const float*)d_in[2];
    const float* wproj = (const float*)d_in[3];
    const float* bproj = (const float*)d_in[4];
    const float* relb  = (const float*)d_in[5];

    u16* wqkvT  = (u16*)d_ws;                 // 768*256 u16
    u16* wprojT = wqkvT + 768 * 256;          // 256*256 u16

    prep_weights<<<1024, 256, 0, stream>>>(wqkv, wproj, wqkvT, wprojT);

    const int nwin = in_sizes[0] / (W * D);   // 4096
    win_attn_final2<<<nwin, 512, 0, stream>>>(x, bqkv, bproj, relb, wqkvT, wprojT, (float*)d_out);
}

// Round 25
// 321.003 us; speedup vs baseline: 1.0336x; 1.0336x over previous
//
#include <hip/hip_runtime.h>
#include <hip/hip_bf16.h>

#define W 64
#define D 256
#define NH 8

typedef unsigned short u16;
typedef unsigned int u32;
typedef __attribute__((ext_vector_type(8))) short bf16x8;
typedef __attribute__((ext_vector_type(4))) float f32x4;

// Native RNE f32->bf16 cast: compiler emits v_cvt_pk_bf16_f32 for pairs.
__device__ __forceinline__ u16 bfc(float f) {
    __hip_bfloat16 h = __float2bfloat16(f);
    return *reinterpret_cast<u16*>(&h);
}

// Sum over the 16-lane DPP row (VALU pipe, not DS): ror8, ror4, quad_perms.
__device__ __forceinline__ float row16_sum(float x) {
    int t;
    t = __builtin_amdgcn_update_dpp(0, __builtin_bit_cast(int, x), 0x128, 0xf, 0xf, true); // row_ror:8
    x += __builtin_bit_cast(float, t);
    t = __builtin_amdgcn_update_dpp(0, __builtin_bit_cast(int, x), 0x124, 0xf, 0xf, true); // row_ror:4
    x += __builtin_bit_cast(float, t);
    t = __builtin_amdgcn_update_dpp(0, __builtin_bit_cast(int, x), 78, 0xf, 0xf, true);    // quad_perm [2,3,0,1]
    x += __builtin_bit_cast(float, t);
    t = __builtin_amdgcn_update_dpp(0, __builtin_bit_cast(int, x), 177, 0xf, 0xf, true);   // quad_perm [1,0,3,2]
    x += __builtin_bit_cast(float, t);
    return x;
}

// ---------------- LDS layout (bytes) ----------------
// xs   : [64][264] u16   x bf16 staging; dead after QKV; aliased by attn_out 33792
// buf  : per-wave [16][72] u16 transposer (q/k 2-pass, v 2-pass, P)           2304 x 8
// bias : [8][128] f32 rel-pos bias table                                      4096
// total 56320 -> 2 blocks/CU (register-capped: 64 VGPR + ~32 AGPR = 96/wave).
// FINAL = R19 (best measured: 319.3 / 321.1 us across two runs):
//  - consistent contraction-index permutations (R12-verified algebra):
//    q/k channel 16b+a at column 2a+b (same sigma on Q,K -> S exact);
//    P/v token 16b+a at column 4a+b (same sigma on P,V -> PV exact)
//    -> packed u32/b64 transposer writes (no same-dword scalar stores)
//  - DPP 16-lane reduce (off the DS pipe), native bf16 casts,
//    scale folded into q, bias table in LDS
//  - full lgkmcnt(0) drains verbatim: the no-spill regalloc anchor
//    (R9/R13/R14/R16/R22: removal/replacement/perturbation all spill)
//  - scalar-scatter proj epilogue (R24's coalesced variant was -10us)
// Structural latency floor, NOT a HW roofline (MfmaUtil 19%, HBM 15%):
// occupancy is walled by registers (6 waves/SIMD needs <=85 regs: spills),
// LDS (3 blk/CU needs <=54.6KB: minimum is 52.2 + bias), and 8-wave block
// granularity. Phase-level nulls: VALU (R17), softmax path (R18), ao-sigma
// (R20), drain diet (R21), epilogue coalesce (R24). Splits/decomps: R4/R15
// (traffic), R3/R6/R8/R11/R14 (spill).
#define XS_ROW 264
#define BUF_ROW 72
#define OFF_BUF 33792
#define OFF_BIAS 52224

__global__ __launch_bounds__(512, 4) void win_attn_final(
    const float* __restrict__ x, const float* __restrict__ bqkv,
    const float* __restrict__ bproj, const float* __restrict__ relb,
    const u16* __restrict__ wqkvT, const u16* __restrict__ wprojT,
    float* __restrict__ out)
{
    __shared__ __align__(16) char smem[56320];

    const int tid  = threadIdx.x;
    const int lane = tid & 63;
    const int h    = tid >> 6;      // wave index == head
    const int l15  = lane & 15;
    const int g    = lane >> 4;
    const int w    = blockIdx.x;

    u16*   xs      = (u16*)smem;
    u16*   buf     = (u16*)(smem + OFF_BUF) + h * 16 * BUF_ROW;
    float* bias_ld = (float*)(smem + OFF_BIAS);

    const f32x4 z4 = {0.f, 0.f, 0.f, 0.f};
    const float scale = 0.17677669529663687f;   // 1/sqrt(32)

    // ---------- Phase 0: bias table + stage x window -> LDS bf16 ----------
    for (int i = tid; i < NH * 127; i += 512)
        bias_ld[(i / 127) * 128 + (i % 127)] = relb[i];

    const float* xw = x + (size_t)w * (W * D);
    #pragma unroll
    for (int i = 0; i < 8; ++i) {
        int e = i * 2048 + tid * 4;
        int row = e >> 8, col = e & 255;
        float4 v = *(const float4*)(xw + e);
        ushort4 b;
        b.x = bfc(v.x); b.y = bfc(v.y); b.z = bfc(v.z); b.w = bfc(v.w);
        *(ushort4*)(xs + row * XS_ROW + col) = b;
    }
    __syncthreads();

    // ---------- Phase 1: QKV for head h; fragments kept in registers ----------
    bf16x8 qf[4], kf[4], vf[2][2];

    #pragma unroll
    for (int mat = 0; mat < 3; ++mat) {
        f32x4 acc[2][4];
        #pragma unroll
        for (int ct = 0; ct < 2; ++ct)
            #pragma unroll
            for (int rt = 0; rt < 4; ++rt)
                acc[ct][rt] = z4;

        const u16* bp0 = wqkvT + (size_t)(mat * 256 + h * 32 + l15) * 256;
        const u16* bp1 = bp0 + 16 * 256;
        #pragma unroll
        for (int ks = 0; ks < 8; ++ks) {
            bf16x8 b0 = *(const bf16x8*)(bp0 + ks * 32 + g * 8);
            bf16x8 b1 = *(const bf16x8*)(bp1 + ks * 32 + g * 8);
            #pragma unroll
            for (int rt = 0; rt < 4; ++rt) {
                bf16x8 a = *(const bf16x8*)(xs + (16 * rt + l15) * XS_ROW + ks * 32 + g * 8);
                acc[0][rt] = __builtin_amdgcn_mfma_f32_16x16x32_bf16(a, b0, acc[0][rt], 0, 0, 0);
                acc[1][rt] = __builtin_amdgcn_mfma_f32_16x16x32_bf16(a, b1, acc[1][rt], 0, 0, 0);
            }
        }
        const float bias0 = bqkv[mat * 256 + h * 32 + l15];
        const float bias1 = bqkv[mat * 256 + h * 32 + 16 + l15];

        asm volatile("s_waitcnt lgkmcnt(0)" ::: "memory");   // WAR: prior buf reads done
        if (mat < 2) {
            // sigma32: channel 16*ct + l15 -> column 2*l15 + ct. Packed u32 writes.
            // q gets scale folded in; k unscaled. 2 row-tiles per pass.
            const float mul = (mat == 0) ? scale : 1.0f;
            #pragma unroll
            for (int rp = 0; rp < 2; ++rp) {
                #pragma unroll
                for (int rtl = 0; rtl < 2; ++rtl)
                    #pragma unroll
                    for (int r = 0; r < 4; ++r) {
                        u32 lo = bfc((acc[0][2 * rp + rtl][r] + bias0) * mul);
                        u32 hi = bfc((acc[1][2 * rp + rtl][r] + bias1) * mul);
                        *(u32*)(buf + (4 * g + r) * BUF_ROW + rtl * 32 + 2 * l15) =
                            lo | (hi << 16);
                    }
                asm volatile("s_waitcnt lgkmcnt(0)" ::: "memory");
                #pragma unroll
                for (int rtl = 0; rtl < 2; ++rtl) {
                    bf16x8 fr = *(const bf16x8*)(buf + l15 * BUF_ROW + rtl * 32 + g * 8);
                    if (mat == 0) qf[2 * rp + rtl] = fr; else kf[2 * rp + rtl] = fr;
                }
                asm volatile("s_waitcnt lgkmcnt(0)" ::: "memory");   // WAR before next pass
            }
        } else {
            // sigma64 on tokens: token t -> column 4*(t&15) + (t>>4).
            // t = 16*rt + 4*g + r2 -> column 16*g + 4*r2 + rt: pack across rt.
            #pragma unroll
            for (int cd = 0; cd < 2; ++cd) {
                const float bias = cd ? bias1 : bias0;
                #pragma unroll
                for (int r2 = 0; r2 < 4; ++r2) {
                    ushort4 pk;
                    pk.x = bfc(acc[cd][0][r2] + bias);
                    pk.y = bfc(acc[cd][1][r2] + bias);
                    pk.z = bfc(acc[cd][2][r2] + bias);
                    pk.w = bfc(acc[cd][3][r2] + bias);
                    *(ushort4*)(buf + l15 * BUF_ROW + 16 * g + 4 * r2) = pk;
                }
                asm volatile("s_waitcnt lgkmcnt(0)" ::: "memory");
                #pragma unroll
                for (int ks = 0; ks < 2; ++ks)
                    vf[ks][cd] = *(const bf16x8*)(buf + l15 * BUF_ROW + ks * 32 + g * 8);
                asm volatile("s_waitcnt lgkmcnt(0)" ::: "memory");   // WAR before next pass
            }
        }
    }
    __syncthreads();   // all xs reads done -> ao may alias xs

    // ---------- Phase 2: attention (wave-private; P via buf; bias via LDS) ----------
    const float* b2 = bias_ld + h * 128;
    u16* ao = xs;

    #pragma unroll
    for (int rt = 0; rt < 4; ++rt) {
        f32x4 s[4];
        #pragma unroll
        for (int ct = 0; ct < 4; ++ct)
            s[ct] = __builtin_amdgcn_mfma_f32_16x16x32_bf16(qf[rt], kf[ct], z4, 0, 0, 0);

        asm volatile("s_waitcnt lgkmcnt(0)" ::: "memory");   // WAR: prev rt's pf reads done
        float psum[4];
        #pragma unroll
        for (int r = 0; r < 4; ++r) {
            const int qtok = 16 * rt + 4 * g + r;
            // P[q][k]: token k = 16*ct + l15 stored at column 4*l15 + ct (sigma64)
            float e0 = __expf(s[0][r] + b2[     l15 - qtok + 63]);
            float e1 = __expf(s[1][r] + b2[16 + l15 - qtok + 63]);
            float e2 = __expf(s[2][r] + b2[32 + l15 - qtok + 63]);
            float e3 = __expf(s[3][r] + b2[48 + l15 - qtok + 63]);
            psum[r] = (e0 + e1) + (e2 + e3);
            ushort4 pk;
            pk.x = bfc(e0); pk.y = bfc(e1); pk.z = bfc(e2); pk.w = bfc(e3);
            *(ushort4*)(buf + (4 * g + r) * BUF_ROW + 4 * l15) = pk;
        }
        float inv[4];
        #pragma unroll
        for (int r = 0; r < 4; ++r)
            inv[r] = 1.0f / row16_sum(psum[r]);

        asm volatile("s_waitcnt lgkmcnt(0)" ::: "memory");
        bf16x8 pf0 = *(const bf16x8*)(buf + l15 * BUF_ROW + g * 8);
        bf16x8 pf1 = *(const bf16x8*)(buf + l15 * BUF_ROW + 32 + g * 8);
        #pragma unroll
        for (int cd = 0; cd < 2; ++cd) {
            f32x4 o = __builtin_amdgcn_mfma_f32_16x16x32_bf16(pf0, vf[0][cd], z4, 0, 0, 0);
            o = __builtin_amdgcn_mfma_f32_16x16x32_bf16(pf1, vf[1][cd], o, 0, 0, 0);
            #pragma unroll
            for (int r = 0; r < 4; ++r)
                ao[(16 * rt + 4 * g + r) * XS_ROW + h * 32 + cd * 16 + l15] = bfc(o[r] * inv[r]);
        }
        asm volatile("s_waitcnt lgkmcnt(0)" ::: "memory");   // WAR before next rt
    }
    __syncthreads();   // ao complete (cross-wave input to proj)

    // ---------- Phase 3: output projection (wave h -> cols h*32..+31) ----------
    f32x4 pacc[2][4];
    #pragma unroll
    for (int ct = 0; ct < 2; ++ct)
        #pragma unroll
        for (int rt = 0; rt < 4; ++rt)
            pacc[ct][rt] = z4;

    const u16* pp0 = wprojT + (size_t)(h * 32 + l15) * 256;
    const u16* pp1 = pp0 + 16 * 256;
    #pragma unroll
    for (int ks = 0; ks < 8; ++ks) {
        bf16x8 b0 = *(const bf16x8*)(pp0 + ks * 32 + g * 8);
        bf16x8 b1 = *(const bf16x8*)(pp1 + ks * 32 + g * 8);
        #pragma unroll
        for (int rt = 0; rt < 4; ++rt) {
            bf16x8 a = *(const bf16x8*)(ao + (16 * rt + l15) * XS_ROW + ks * 32 + g * 8);
            pacc[0][rt] = __builtin_amdgcn_mfma_f32_16x16x32_bf16(a, b0, pacc[0][rt], 0, 0, 0);
            pacc[1][rt] = __builtin_amdgcn_mfma_f32_16x16x32_bf16(a, b1, pacc[1][rt], 0, 0, 0);
        }
    }
    float* outw = out + (size_t)w * (W * D);
    #pragma unroll
    for (int ct = 0; ct < 2; ++ct) {
        const int n = h * 32 + ct * 16 + l15;
        const float bp = bproj[n];
        #pragma unroll
        for (int rt = 0; rt < 4; ++rt)
            #pragma unroll
            for (int r = 0; r < 4; ++r)
                outw[(16 * rt + 4 * g + r) * D + n] = pacc[ct][rt][r] + bp;
    }
}

// Transpose + bf16-convert the weight matrices into workspace (L2-resident).
__global__ void prep_weights(const float* __restrict__ wqkv, const float* __restrict__ wproj,
                             u16* __restrict__ wqkvT, u16* __restrict__ wprojT)
{
    int i = blockIdx.x * 256 + threadIdx.x;
    if (i < 768 * 256) {
        int n = i >> 8, kk = i & 255;
        wqkvT[i] = bfc(wqkv[kk * 768 + n]);
    } else {
        int j = i - 768 * 256;
        int n = j >> 8, kk = j & 255;
        wprojT[j] = bfc(wproj[kk * 256 + n]);
    }
}

extern "C" void kernel_launch(void* const* d_in, const int* in_sizes, int n_in,
                              void* d_out, int out_size, void* d_ws, size_t ws_size,
                              hipStream_t stream)
{
    const float* x     = (const float*)d_in[0];
    const float* wqkv  = (const float*)d_in[1];
    const float* bqkv  = (const float*)d_in[2];
    const float* wproj = (const float*)d_in[3];
    const float* bproj = (const float*)d_in[4];
    const float* relb  = (const float*)d_in[5];

    u16* wqkvT  = (u16*)d_ws;                 // 768*256 u16
    u16* wprojT = wqkvT + 768 * 256;          // 256*256 u16

    prep_weights<<<1024, 256, 0, stream>>>(wqkv, wproj, wqkvT, wprojT);

    const int nwin = in_sizes[0] / (W * D);   // 4096
    win_attn_final<<<nwin, 512, 0, stream>>>(x, bqkv, bproj, relb, wqkvT, wprojT, (float*)d_out);
}